// Round 2
// baseline (363.073 us; speedup 1.0000x reference)
//
#include <hip/hip_runtime.h>
#include <stdint.h>

// ---------------------------------------------------------------------------
// SAM encoder attention, MI355X/gfx950.
// Pipeline: convert(fp32->bf16) -> qkv_gemm (bf16 MFMA, writes q,k bf16 [n][p][d]
// and v transposed [n][d][p]) -> rel_kernel x2 (rel_h/rel_w bias tables) ->
// flash_kernel (online-softmax attention, 64-query x 64-key tiles) -> proj_gemm.
//
// NOTE on rel_w: the reference does `attn + rel_w[:, :, :, None, :]` where
// rel_w is (B,nH,H,W,Wk) -> broadcast shape (B,nH,H,1,W,Wk), which aligns
// rel_w's w-axis with the KEY-ROW axis h2. So the bias at (h,w,h2,w2) is
// rel_h[h,w,h2] + rel_w[h, h2, w2]  -- rel_w does NOT depend on query w.
// In flash (block = one query row h, key tile t = h2) rel_w is a per-tile
// 64-vector rel_w[n][h*64+t][w2], shared by all 64 queries of the block.
//
// All MFMA: v_mfma_f32_16x16x32_bf16. Layouts per verified m89/m120 mappings:
//   A: m=lane&15, k=quad*8+j ; B: n=lane&15, k=quad*8+j ; C/D: col=lane&15,
//   row=quad*4+reg.
// ---------------------------------------------------------------------------

typedef unsigned short ushort_t;
typedef __attribute__((ext_vector_type(8))) __bf16 bf16x8;
typedef __attribute__((ext_vector_type(4))) float f32x4;

#define NHD 12
#define HD 64
#define CIN 768
#define HWP 4096
#define SCALE 0.125f

__device__ __forceinline__ ushort_t f2bf(float f) {
  union { float f; unsigned u; } v; v.f = f;
  unsigned r = (v.u + 0x7fffu + ((v.u >> 16) & 1u)) >> 16;  // RNE
  return (ushort_t)r;
}
__device__ __forceinline__ float bf2f(ushort_t h) {
  union { unsigned u; float f; } v; v.u = ((unsigned)h) << 16;
  return v.f;
}
__device__ __forceinline__ f32x4 mfma16(bf16x8 a, bf16x8 b, f32x4 c) {
  return __builtin_amdgcn_mfma_f32_16x16x32_bf16(a, b, c, 0, 0, 0);
}

// ---------------------------------------------------------------------------
// Convert all fp32 inputs to bf16 staging buffers; build concatenated qkv bias.
// ---------------------------------------------------------------------------
__global__ void convert_kernel(const float* __restrict__ x,
                               const float* __restrict__ wq, const float* __restrict__ bq,
                               const float* __restrict__ wk, const float* __restrict__ bk,
                               const float* __restrict__ wv, const float* __restrict__ bv,
                               const float* __restrict__ rph, const float* __restrict__ rpw,
                               const float* __restrict__ pw,
                               ushort_t* __restrict__ x_bf, ushort_t* __restrict__ w_bf,
                               ushort_t* __restrict__ pw_bf, ushort_t* __restrict__ rph_bf,
                               ushort_t* __restrict__ rpw_bf, float* __restrict__ bias_all) {
  const int i = blockIdx.x * blockDim.x + threadIdx.x;
  const int stride = gridDim.x * blockDim.x;
  const int NX = HWP * CIN;        // 3145728
  const int NW = NHD * HD * CIN;   // 589824
  const int NR = 127 * HD;         // 8128
  for (int t = i; t < NX; t += stride) x_bf[t] = f2bf(x[t]);
  for (int t = i; t < NW; t += stride) {
    w_bf[t]          = f2bf(wq[t]);
    w_bf[NW + t]     = f2bf(wk[t]);
    w_bf[2 * NW + t] = f2bf(wv[t]);
    pw_bf[t]         = f2bf(pw[t]);
  }
  for (int t = i; t < NR; t += stride) { rph_bf[t] = f2bf(rph[t]); rpw_bf[t] = f2bf(rpw[t]); }
  for (int t = i; t < NHD * HD; t += stride) {
    bias_all[t]        = bq[t];
    bias_all[768 + t]  = bk[t];
    bias_all[1536 + t] = bv[t];
  }
}

// ---------------------------------------------------------------------------
// QKV GEMM: C(4096 x 2304) = X(4096x768) * W^T(2304x768), NT, bf16 MFMA.
// 128x128 tile, BK=32, 256 threads (4 waves 2x2, each 64x64). LDS row stride 40
// (80B) -> 2-way bank aliasing only (free per m136).
// Epilogue adds bias and scatters: q,k -> [n][p][d] bf16 ; v -> [n][d][p] bf16.
// ---------------------------------------------------------------------------
__global__ __launch_bounds__(256) void qkv_gemm(
    const ushort_t* __restrict__ x_bf, const ushort_t* __restrict__ w_bf,
    const float* __restrict__ bias_all,
    ushort_t* __restrict__ q_bf, ushort_t* __restrict__ k_bf, ushort_t* __restrict__ v_t) {
  __shared__ ushort_t As[128][40];
  __shared__ ushort_t Bs[128][40];
  const int m0 = blockIdx.x * 128, n0 = blockIdx.y * 128;
  const int tid = threadIdx.x;
  const int lane = tid & 63, wid = tid >> 6;
  const int l15 = lane & 15, quad = lane >> 4;
  const int wm = (wid >> 1) * 64, wn = (wid & 1) * 64;

  f32x4 acc[4][4];
#pragma unroll
  for (int a = 0; a < 4; a++)
#pragma unroll
    for (int b = 0; b < 4; b++) acc[a][b] = (f32x4){0.f, 0.f, 0.f, 0.f};

  const int sr = tid >> 2;          // 0..63
  const int sc = (tid & 3) * 8;     // 0,8,16,24
  for (int kt = 0; kt < 24; kt++) {
#pragma unroll
    for (int h = 0; h < 2; h++) {
      int row = sr + h * 64;
      *(uint4*)&As[row][sc] = *(const uint4*)&x_bf[(m0 + row) * CIN + kt * 32 + sc];
      *(uint4*)&Bs[row][sc] = *(const uint4*)&w_bf[(n0 + row) * CIN + kt * 32 + sc];
    }
    __syncthreads();
    bf16x8 af[4], bfr[4];
#pragma unroll
    for (int mb = 0; mb < 4; mb++)
      af[mb] = *reinterpret_cast<const bf16x8*>(&As[wm + mb * 16 + l15][quad * 8]);
#pragma unroll
    for (int nb = 0; nb < 4; nb++)
      bfr[nb] = *reinterpret_cast<const bf16x8*>(&Bs[wn + nb * 16 + l15][quad * 8]);
#pragma unroll
    for (int mb = 0; mb < 4; mb++)
#pragma unroll
      for (int nb = 0; nb < 4; nb++)
        acc[mb][nb] = mfma16(af[mb], bfr[nb], acc[mb][nb]);
    __syncthreads();
  }

#pragma unroll
  for (int mb = 0; mb < 4; mb++) {
#pragma unroll
    for (int nb = 0; nb < 4; nb++) {
      const int colg = n0 + wn + nb * 16 + l15;   // 0..2303
      const float bias = bias_all[colg];
#pragma unroll
      for (int r = 0; r < 4; r++) {
        const int rowg = m0 + wm + mb * 16 + quad * 4 + r;  // p
        const ushort_t h = f2bf(acc[mb][nb][r] + bias);
        if (colg < 768) {
          q_bf[((colg >> 6) * HWP + rowg) * HD + (colg & 63)] = h;
        } else if (colg < 1536) {
          const int j = colg - 768;
          k_bf[((j >> 6) * HWP + rowg) * HD + (j & 63)] = h;
        } else {
          const int j = colg - 1536;          // n*64+d
          v_t[j * HWP + rowg] = h;            // [n][d][p]
        }
      }
    }
  }
}

// ---------------------------------------------------------------------------
// rel bias tables. mode 0: rel_h[n][p=h*64+w][t] = sum_c q[n][p][c]*rph[63+h-t][c]
//                 mode 1: rel_w[n][p=h*64+w][w2] = sum_c q[n][p][c]*rpw[63+w-w2][c]
// One block per (n, h) / (n, w): 64x64 = (64 x 64c) * (64 x 64c)^T via MFMA.
// ---------------------------------------------------------------------------
__global__ __launch_bounds__(256) void rel_kernel(
    const ushort_t* __restrict__ q_bf, const ushort_t* __restrict__ rp_bf,
    ushort_t* __restrict__ rel_out, int mode) {
  const int bx = blockIdx.x;
  const int n = bx >> 6, hw = bx & 63;
  const int tid = threadIdx.x;
  const int lane = tid & 63, wid = tid >> 6;
  const int l15 = lane & 15, quad = lane >> 4;

  __shared__ ushort_t Qs[64][72];
  __shared__ ushort_t Rs[64][72];

  const int r0 = tid >> 3, c8 = (tid & 7) * 8;
#pragma unroll
  for (int h = 0; h < 2; h++) {
    const int r = r0 + h * 32;
    const int p = (mode == 0) ? (hw * 64 + r) : (r * 64 + hw);
    *(uint4*)&Qs[r][c8] = *(const uint4*)&q_bf[(n * HWP + p) * HD + c8];
    *(uint4*)&Rs[r][c8] = *(const uint4*)&rp_bf[(63 + hw - r) * HD + c8];
  }
  __syncthreads();

  bf16x8 a0 = *reinterpret_cast<const bf16x8*>(&Qs[wid * 16 + l15][quad * 8]);
  bf16x8 a1 = *reinterpret_cast<const bf16x8*>(&Qs[wid * 16 + l15][32 + quad * 8]);
#pragma unroll
  for (int nb = 0; nb < 4; nb++) {
    bf16x8 b0 = *reinterpret_cast<const bf16x8*>(&Rs[nb * 16 + l15][quad * 8]);
    bf16x8 b1 = *reinterpret_cast<const bf16x8*>(&Rs[nb * 16 + l15][32 + quad * 8]);
    f32x4 c = (f32x4){0.f, 0.f, 0.f, 0.f};
    c = mfma16(a0, b0, c);
    c = mfma16(a1, b1, c);
#pragma unroll
    for (int r = 0; r < 4; r++) {
      const int lr = wid * 16 + quad * 4 + r;
      const int col = nb * 16 + l15;
      const int p2 = (mode == 0) ? (hw * 64 + lr) : (lr * 64 + hw);
      rel_out[(n * HWP + p2) * 64 + col] = f2bf(c[r]);
    }
  }
}

// ---------------------------------------------------------------------------
// Flash attention. Block = (head n, query row h = qt). 64-key tiles (t = key
// row h2). Bias = rel_h[q][t] (per-query scalar) + rel_w[n][h*64+t][w2]
// (per-tile vector, query-independent -- see header note on the reference's
// broadcast). Online softmax in fp32; P round-trips LDS as bf16 for PV
// A-fragments. LDS ~44 KB -> 3 blocks/CU.
// ---------------------------------------------------------------------------
__global__ __launch_bounds__(256) void flash_kernel(
    const ushort_t* __restrict__ q_bf, const ushort_t* __restrict__ k_bf,
    const ushort_t* __restrict__ v_t, const ushort_t* __restrict__ rel_h,
    const ushort_t* __restrict__ rel_w, ushort_t* __restrict__ ao_bf) {
  const int bx = blockIdx.x;
  const int n = bx >> 6, qt = bx & 63;   // qt = query image row h
  const int q0 = qt * 64;
  const int tid = threadIdx.x;
  const int lane = tid & 63, wid = tid >> 6;
  const int l15 = lane & 15, quad = lane >> 4;

  __shared__ ushort_t Qs[64][72], Ks[64][72], Vt[64][72], Ps[64][72];
  __shared__ ushort_t RHs[64][64];

  const int r0 = tid >> 3, c8 = (tid & 7) * 8;
#pragma unroll
  for (int h = 0; h < 2; h++) {
    const int r = r0 + h * 32;
    *(uint4*)&Qs[r][c8]  = *(const uint4*)&q_bf[(n * HWP + q0 + r) * HD + c8];
    *(uint4*)&RHs[r][c8] = *(const uint4*)&rel_h[(n * HWP + q0 + r) * 64 + c8];
  }
  __syncthreads();

  const bf16x8 qa0 = *reinterpret_cast<const bf16x8*>(&Qs[wid * 16 + l15][quad * 8]);
  const bf16x8 qa1 = *reinterpret_cast<const bf16x8*>(&Qs[wid * 16 + l15][32 + quad * 8]);

  f32x4 o[4];
  float m_i[4], l_i[4];
#pragma unroll
  for (int r = 0; r < 4; r++) { m_i[r] = -1e30f; l_i[r] = 0.f; }
#pragma unroll
  for (int d = 0; d < 4; d++) o[d] = (f32x4){0.f, 0.f, 0.f, 0.f};

  for (int t = 0; t < 64; t++) {
#pragma unroll
    for (int h = 0; h < 2; h++) {
      const int r = r0 + h * 32;
      *(uint4*)&Ks[r][c8] = *(const uint4*)&k_bf[(n * HWP + t * 64 + r) * HD + c8];
      *(uint4*)&Vt[r][c8] = *(const uint4*)&v_t[(n * HD + r) * HWP + t * 64 + c8];
    }
    // per-tile rel_w bias: query-independent, depends on (t, w2) only
    float rw[4];
#pragma unroll
    for (int nb = 0; nb < 4; nb++)
      rw[nb] = bf2f(rel_w[((n * HWP + q0 + t) << 6) + nb * 16 + l15]);
    __syncthreads();

    // S = Q K^T (16 q-rows per wave x 64 key-cols)
    f32x4 s[4];
#pragma unroll
    for (int nb = 0; nb < 4; nb++) {
      bf16x8 b0 = *reinterpret_cast<const bf16x8*>(&Ks[nb * 16 + l15][quad * 8]);
      bf16x8 b1 = *reinterpret_cast<const bf16x8*>(&Ks[nb * 16 + l15][32 + quad * 8]);
      f32x4 c = (f32x4){0.f, 0.f, 0.f, 0.f};
      c = mfma16(qa0, b0, c);
      c = mfma16(qa1, b1, c);
      s[nb] = c;
    }
    // scale + rel-pos bias
    float rh[4];
#pragma unroll
    for (int r = 0; r < 4; r++) rh[r] = bf2f(RHs[wid * 16 + quad * 4 + r][t]);
#pragma unroll
    for (int nb = 0; nb < 4; nb++) {
#pragma unroll
      for (int r = 0; r < 4; r++)
        s[nb][r] = s[nb][r] * SCALE + rh[r] + rw[nb];
    }
    // online softmax (row = quad*4+r, shared by the 16 lanes of a quad)
    float rm[4];
#pragma unroll
    for (int r = 0; r < 4; r++)
      rm[r] = fmaxf(fmaxf(s[0][r], s[1][r]), fmaxf(s[2][r], s[3][r]));
#pragma unroll
    for (int mk = 1; mk < 16; mk <<= 1)
#pragma unroll
      for (int r = 0; r < 4; r++) rm[r] = fmaxf(rm[r], __shfl_xor(rm[r], mk, 64));
    float alpha[4];
#pragma unroll
    for (int r = 0; r < 4; r++) {
      const float nm = fmaxf(m_i[r], rm[r]);
      alpha[r] = __expf(m_i[r] - nm);
      m_i[r] = nm;
    }
    float rs[4] = {0.f, 0.f, 0.f, 0.f};
#pragma unroll
    for (int nb = 0; nb < 4; nb++)
#pragma unroll
      for (int r = 0; r < 4; r++) {
        const float p = __expf(s[nb][r] - m_i[r]);
        s[nb][r] = p;
        rs[r] += p;
      }
#pragma unroll
    for (int mk = 1; mk < 16; mk <<= 1)
#pragma unroll
      for (int r = 0; r < 4; r++) rs[r] += __shfl_xor(rs[r], mk, 64);
#pragma unroll
    for (int r = 0; r < 4; r++) l_i[r] = l_i[r] * alpha[r] + rs[r];
#pragma unroll
    for (int d = 0; d < 4; d++)
#pragma unroll
      for (int r = 0; r < 4; r++) o[d][r] *= alpha[r];
    // P -> LDS (C-layout scatter -> A-layout gather)
#pragma unroll
    for (int nb = 0; nb < 4; nb++)
#pragma unroll
      for (int r = 0; r < 4; r++)
        Ps[wid * 16 + quad * 4 + r][nb * 16 + l15] = f2bf(s[nb][r]);
    __syncthreads();

    const bf16x8 pa0 = *reinterpret_cast<const bf16x8*>(&Ps[wid * 16 + l15][quad * 8]);
    const bf16x8 pa1 = *reinterpret_cast<const bf16x8*>(&Ps[wid * 16 + l15][32 + quad * 8]);
#pragma unroll
    for (int d = 0; d < 4; d++) {
      bf16x8 vb0 = *reinterpret_cast<const bf16x8*>(&Vt[d * 16 + l15][quad * 8]);
      bf16x8 vb1 = *reinterpret_cast<const bf16x8*>(&Vt[d * 16 + l15][32 + quad * 8]);
      o[d] = mfma16(pa0, vb0, o[d]);
      o[d] = mfma16(pa1, vb1, o[d]);
    }
    __syncthreads();  // protect Ks/Vt/Ps before next tile's staging
  }

#pragma unroll
  for (int d = 0; d < 4; d++)
#pragma unroll
    for (int r = 0; r < 4; r++) {
      const int qr = q0 + wid * 16 + quad * 4 + r;
      ao_bf[qr * 768 + n * 64 + d * 16 + l15] = f2bf(o[d][r] / l_i[r]);
    }
}

// ---------------------------------------------------------------------------
// Output projection: out(4096x768) = AO(4096x768) * PW^T(768x768) + pb, fp32 out.
// ---------------------------------------------------------------------------
__global__ __launch_bounds__(256) void proj_gemm(
    const ushort_t* __restrict__ ao_bf, const ushort_t* __restrict__ pw_bf,
    const float* __restrict__ pb, float* __restrict__ out) {
  __shared__ ushort_t As[128][40];
  __shared__ ushort_t Bs[128][40];
  const int m0 = blockIdx.x * 128, n0 = blockIdx.y * 128;
  const int tid = threadIdx.x;
  const int lane = tid & 63, wid = tid >> 6;
  const int l15 = lane & 15, quad = lane >> 4;
  const int wm = (wid >> 1) * 64, wn = (wid & 1) * 64;

  f32x4 acc[4][4];
#pragma unroll
  for (int a = 0; a < 4; a++)
#pragma unroll
    for (int b = 0; b < 4; b++) acc[a][b] = (f32x4){0.f, 0.f, 0.f, 0.f};

  const int sr = tid >> 2;
  const int sc = (tid & 3) * 8;
  for (int kt = 0; kt < 24; kt++) {
#pragma unroll
    for (int h = 0; h < 2; h++) {
      int row = sr + h * 64;
      *(uint4*)&As[row][sc] = *(const uint4*)&ao_bf[(m0 + row) * CIN + kt * 32 + sc];
      *(uint4*)&Bs[row][sc] = *(const uint4*)&pw_bf[(n0 + row) * CIN + kt * 32 + sc];
    }
    __syncthreads();
    bf16x8 af[4], bfr[4];
#pragma unroll
    for (int mb = 0; mb < 4; mb++)
      af[mb] = *reinterpret_cast<const bf16x8*>(&As[wm + mb * 16 + l15][quad * 8]);
#pragma unroll
    for (int nb = 0; nb < 4; nb++)
      bfr[nb] = *reinterpret_cast<const bf16x8*>(&Bs[wn + nb * 16 + l15][quad * 8]);
#pragma unroll
    for (int mb = 0; mb < 4; mb++)
#pragma unroll
      for (int nb = 0; nb < 4; nb++)
        acc[mb][nb] = mfma16(af[mb], bfr[nb], acc[mb][nb]);
    __syncthreads();
  }

#pragma unroll
  for (int mb = 0; mb < 4; mb++) {
#pragma unroll
    for (int nb = 0; nb < 4; nb++) {
      const int colg = n0 + wn + nb * 16 + l15;
      const float bias = pb[colg];
#pragma unroll
      for (int r = 0; r < 4; r++) {
        const int rowg = m0 + wm + mb * 16 + quad * 4 + r;
        out[rowg * 768 + colg] = acc[mb][nb][r] + bias;
      }
    }
  }
}

// ---------------------------------------------------------------------------
extern "C" void kernel_launch(void* const* d_in, const int* in_sizes, int n_in,
                              void* d_out, int out_size, void* d_ws, size_t ws_size,
                              hipStream_t stream) {
  (void)in_sizes; (void)n_in; (void)out_size; (void)ws_size;
  const float* x   = (const float*)d_in[0];
  const float* wq  = (const float*)d_in[1];
  const float* bq  = (const float*)d_in[2];
  const float* wk  = (const float*)d_in[3];
  const float* bk  = (const float*)d_in[4];
  const float* wv  = (const float*)d_in[5];
  const float* bv  = (const float*)d_in[6];
  const float* rph = (const float*)d_in[7];
  const float* rpw = (const float*)d_in[8];
  const float* pw  = (const float*)d_in[9];
  const float* pb  = (const float*)d_in[10];
  float* out = (float*)d_out;

  char* ws = (char*)d_ws;
  size_t off = 0;
  auto alloc = [&](size_t bytes) -> char* {
    char* p = ws + off;
    off += (bytes + 255) & ~(size_t)255;
    return p;
  };
  ushort_t* x_bf   = (ushort_t*)alloc((size_t)HWP * CIN * 2);        // 6291456
  ushort_t* w_bf   = (ushort_t*)alloc((size_t)3 * NHD * HD * CIN * 2); // 3538944
  ushort_t* pw_bf  = (ushort_t*)alloc((size_t)NHD * HD * CIN * 2);   // 1179648
  ushort_t* rph_bf = (ushort_t*)alloc((size_t)127 * HD * 2);
  ushort_t* rpw_bf = (ushort_t*)alloc((size_t)127 * HD * 2);
  float*    bias_all = (float*)alloc((size_t)3 * NHD * HD * 4);
  ushort_t* q_bf  = (ushort_t*)alloc((size_t)NHD * HWP * HD * 2);    // 6291456
  ushort_t* k_bf  = (ushort_t*)alloc((size_t)NHD * HWP * HD * 2);
  ushort_t* v_t   = (ushort_t*)alloc((size_t)NHD * HWP * HD * 2);
  ushort_t* rel_h = (ushort_t*)alloc((size_t)NHD * HWP * 64 * 2);
  ushort_t* rel_w = (ushort_t*)alloc((size_t)NHD * HWP * 64 * 2);
  ushort_t* ao_bf = (ushort_t*)alloc((size_t)HWP * CIN * 2);
  // total ~47 MB

  convert_kernel<<<dim3(2048), dim3(256), 0, stream>>>(
      x, wq, bq, wk, bk, wv, bv, rph, rpw, pw,
      x_bf, w_bf, pw_bf, rph_bf, rpw_bf, bias_all);
  qkv_gemm<<<dim3(32, 18), dim3(256), 0, stream>>>(
      x_bf, w_bf, bias_all, q_bf, k_bf, v_t);
  rel_kernel<<<dim3(NHD * 64), dim3(256), 0, stream>>>(q_bf, rph_bf, rel_h, 0);
  rel_kernel<<<dim3(NHD * 64), dim3(256), 0, stream>>>(q_bf, rpw_bf, rel_w, 1);
  flash_kernel<<<dim3(NHD * 64), dim3(256), 0, stream>>>(
      q_bf, k_bf, v_t, rel_h, rel_w, ao_bf);
  proj_gemm<<<dim3(32, 6), dim3(256), 0, stream>>>(ao_bf, pw_bf, pb, out);
}

// Round 3
// 253.875 us; speedup vs baseline: 1.4301x; 1.4301x over previous
//
#include <hip/hip_runtime.h>
#include <stdint.h>

// ---------------------------------------------------------------------------
// SAM encoder attention, MI355X/gfx950.
// convert(fp32->bf16, q pre-scaled by scale*log2e) -> qkv_gemm -> rel_kernel
// (both tables, outputs *8 => rel*log2e) -> flash (S^T/o^T scheme, no-max
// softmax in exp2 domain, wave-local P quadrants) -> proj_gemm.
// MFMA 16x16x32 bf16 only; layouts per verified m89/m120 mappings:
//   A/B: m(n)=lane&15, k=quad*8+j ; C/D: col=lane&15, row=quad*4+reg.
// ---------------------------------------------------------------------------

typedef unsigned short ushort_t;
typedef __attribute__((ext_vector_type(8))) __bf16 bf16x8;
typedef __attribute__((ext_vector_type(4))) float f32x4;

#define NHD 12
#define HD 64
#define CIN 768
#define HWP 4096
#define QPRE 0.18033688f   /* 0.125 * log2(e) */

#if __has_builtin(__builtin_amdgcn_exp2f)
#define EXP2(x) __builtin_amdgcn_exp2f(x)
#else
#define EXP2(x) exp2f(x)
#endif

__device__ __forceinline__ ushort_t f2bf(float f) {
  union { float f; unsigned u; } v; v.f = f;
  unsigned r = (v.u + 0x7fffu + ((v.u >> 16) & 1u)) >> 16;  // RNE
  return (ushort_t)r;
}
__device__ __forceinline__ float bf2f(ushort_t h) {
  union { unsigned u; float f; } v; v.u = ((unsigned)h) << 16;
  return v.f;
}
__device__ __forceinline__ unsigned packbf(float a, float b) {
  // round-half-up bf16 pair pack (lo=a, hi=b)
  unsigned ua = (__float_as_uint(a) + 0x8000u) >> 16;
  unsigned ub = (__float_as_uint(b) + 0x8000u) & 0xffff0000u;
  return ua | ub;
}
__device__ __forceinline__ f32x4 mfma16(bf16x8 a, bf16x8 b, f32x4 c) {
  return __builtin_amdgcn_mfma_f32_16x16x32_bf16(a, b, c, 0, 0, 0);
}

// ---------------------------------------------------------------------------
__global__ void convert_kernel(const float* __restrict__ x,
                               const float* __restrict__ wq, const float* __restrict__ bq,
                               const float* __restrict__ wk, const float* __restrict__ bk,
                               const float* __restrict__ wv, const float* __restrict__ bv,
                               const float* __restrict__ rph, const float* __restrict__ rpw,
                               const float* __restrict__ pw,
                               ushort_t* __restrict__ x_bf, ushort_t* __restrict__ w_bf,
                               ushort_t* __restrict__ pw_bf, ushort_t* __restrict__ rph_bf,
                               ushort_t* __restrict__ rpw_bf, float* __restrict__ bias_all) {
  const int i = blockIdx.x * blockDim.x + threadIdx.x;
  const int stride = gridDim.x * blockDim.x;
  const int NX = HWP * CIN;
  const int NW = NHD * HD * CIN;
  const int NR = 127 * HD;
  for (int t = i; t < NX; t += stride) x_bf[t] = f2bf(x[t]);
  for (int t = i; t < NW; t += stride) {
    w_bf[t]          = f2bf(wq[t]);
    w_bf[NW + t]     = f2bf(wk[t]);
    w_bf[2 * NW + t] = f2bf(wv[t]);
    pw_bf[t]         = f2bf(pw[t]);
  }
  for (int t = i; t < NR; t += stride) { rph_bf[t] = f2bf(rph[t]); rpw_bf[t] = f2bf(rpw[t]); }
  for (int t = i; t < NHD * HD; t += stride) {
    bias_all[t]        = bq[t];
    bias_all[768 + t]  = bk[t];
    bias_all[1536 + t] = bv[t];
  }
}

// ---------------------------------------------------------------------------
// QKV GEMM. q stored pre-scaled by QPRE (scale*log2e); k, v unscaled.
// ---------------------------------------------------------------------------
__global__ __launch_bounds__(256) void qkv_gemm(
    const ushort_t* __restrict__ x_bf, const ushort_t* __restrict__ w_bf,
    const float* __restrict__ bias_all,
    ushort_t* __restrict__ q_bf, ushort_t* __restrict__ k_bf, ushort_t* __restrict__ v_t) {
  __shared__ ushort_t As[128][40];
  __shared__ ushort_t Bs[128][40];
  const int m0 = blockIdx.x * 128, n0 = blockIdx.y * 128;
  const int tid = threadIdx.x;
  const int lane = tid & 63, wid = tid >> 6;
  const int l15 = lane & 15, quad = lane >> 4;
  const int wm = (wid >> 1) * 64, wn = (wid & 1) * 64;

  f32x4 acc[4][4];
#pragma unroll
  for (int a = 0; a < 4; a++)
#pragma unroll
    for (int b = 0; b < 4; b++) acc[a][b] = (f32x4){0.f, 0.f, 0.f, 0.f};

  const int sr = tid >> 2;
  const int sc = (tid & 3) * 8;
  for (int kt = 0; kt < 24; kt++) {
#pragma unroll
    for (int h = 0; h < 2; h++) {
      int row = sr + h * 64;
      *(uint4*)&As[row][sc] = *(const uint4*)&x_bf[(m0 + row) * CIN + kt * 32 + sc];
      *(uint4*)&Bs[row][sc] = *(const uint4*)&w_bf[(n0 + row) * CIN + kt * 32 + sc];
    }
    __syncthreads();
    bf16x8 af[4], bfr[4];
#pragma unroll
    for (int mb = 0; mb < 4; mb++)
      af[mb] = *reinterpret_cast<const bf16x8*>(&As[wm + mb * 16 + l15][quad * 8]);
#pragma unroll
    for (int nb = 0; nb < 4; nb++)
      bfr[nb] = *reinterpret_cast<const bf16x8*>(&Bs[wn + nb * 16 + l15][quad * 8]);
#pragma unroll
    for (int mb = 0; mb < 4; mb++)
#pragma unroll
      for (int nb = 0; nb < 4; nb++)
        acc[mb][nb] = mfma16(af[mb], bfr[nb], acc[mb][nb]);
    __syncthreads();
  }

#pragma unroll
  for (int mb = 0; mb < 4; mb++) {
#pragma unroll
    for (int nb = 0; nb < 4; nb++) {
      const int colg = n0 + wn + nb * 16 + l15;
      const float bias = bias_all[colg];
#pragma unroll
      for (int r = 0; r < 4; r++) {
        const int rowg = m0 + wm + mb * 16 + quad * 4 + r;
        const float val = acc[mb][nb][r] + bias;
        if (colg < 768) {
          q_bf[((colg >> 6) * HWP + rowg) * HD + (colg & 63)] = f2bf(val * QPRE);
        } else if (colg < 1536) {
          const int j = colg - 768;
          k_bf[((j >> 6) * HWP + rowg) * HD + (j & 63)] = f2bf(val);
        } else {
          const int j = colg - 1536;
          v_t[j * HWP + rowg] = f2bf(val);   // [n][d][p]
        }
      }
    }
  }
}

// ---------------------------------------------------------------------------
// rel tables (both modes in one launch, blockIdx.y = mode).
// q_bf is pre-scaled by QPRE, so output *8 gives rel * log2(e).
// ---------------------------------------------------------------------------
__global__ __launch_bounds__(256) void rel_kernel(
    const ushort_t* __restrict__ q_bf, const ushort_t* __restrict__ rph_bf,
    const ushort_t* __restrict__ rpw_bf,
    ushort_t* __restrict__ rel_h, ushort_t* __restrict__ rel_w) {
  const int mode = blockIdx.y;
  const ushort_t* __restrict__ rp_bf = mode ? rpw_bf : rph_bf;
  ushort_t* __restrict__ rel_out = mode ? rel_w : rel_h;
  const int bx = blockIdx.x;
  const int n = bx >> 6, hw = bx & 63;
  const int tid = threadIdx.x;
  const int lane = tid & 63, wid = tid >> 6;
  const int l15 = lane & 15, quad = lane >> 4;

  __shared__ ushort_t Qs[64][72];
  __shared__ ushort_t Rs[64][72];

  const int r0 = tid >> 3, c8 = (tid & 7) * 8;
#pragma unroll
  for (int h = 0; h < 2; h++) {
    const int r = r0 + h * 32;
    const int p = (mode == 0) ? (hw * 64 + r) : (r * 64 + hw);
    *(uint4*)&Qs[r][c8] = *(const uint4*)&q_bf[(n * HWP + p) * HD + c8];
    *(uint4*)&Rs[r][c8] = *(const uint4*)&rp_bf[(63 + hw - r) * HD + c8];
  }
  __syncthreads();

  bf16x8 a0 = *reinterpret_cast<const bf16x8*>(&Qs[wid * 16 + l15][quad * 8]);
  bf16x8 a1 = *reinterpret_cast<const bf16x8*>(&Qs[wid * 16 + l15][32 + quad * 8]);
#pragma unroll
  for (int nb = 0; nb < 4; nb++) {
    bf16x8 b0 = *reinterpret_cast<const bf16x8*>(&Rs[nb * 16 + l15][quad * 8]);
    bf16x8 b1 = *reinterpret_cast<const bf16x8*>(&Rs[nb * 16 + l15][32 + quad * 8]);
    f32x4 c = (f32x4){0.f, 0.f, 0.f, 0.f};
    c = mfma16(a0, b0, c);
    c = mfma16(a1, b1, c);
#pragma unroll
    for (int r = 0; r < 4; r++) {
      const int lr = wid * 16 + quad * 4 + r;
      const int col = nb * 16 + l15;
      const int p2 = (mode == 0) ? (hw * 64 + lr) : (lr * 64 + hw);
      rel_out[(n * HWP + p2) * 64 + col] = f2bf(c[r] * 8.0f);
    }
  }
}

// ---------------------------------------------------------------------------
// Flash attention, S^T/o^T scheme. Block = (head n, q-row qt). 4 waves in a
// 2x2 grid: wq = q-half, wk2 = key-half of each 64-key tile.
//  S^T[k][q] = K * Q^T (A=K tile rows from LDS, B=Q frags in regs)
//  o^T[d][q] += V^T * P^T (A=Vt rows, B = own P quadrant, wave-local LDS)
// No-max softmax in exp2 domain (|logit*log2e| <~ 3.4, safe in fp32).
// l accumulates per-lane; o accumulates in MFMA C regs across all 64 tiles.
// 2 barriers/tile; next K/V tile prefetched into registers.
// ---------------------------------------------------------------------------
__global__ __launch_bounds__(256, 3) void flash_kernel(
    const ushort_t* __restrict__ q_bf, const ushort_t* __restrict__ k_bf,
    const ushort_t* __restrict__ v_t, const ushort_t* __restrict__ rel_h,
    const ushort_t* __restrict__ rel_w, ushort_t* __restrict__ ao_bf) {
  const int bx = blockIdx.x;
  const int n = bx >> 6, qt = bx & 63;
  const int q0 = qt * 64;
  const int tid = threadIdx.x;
  const int lane = tid & 63, wid = tid >> 6;
  const int l15 = lane & 15, quad = lane >> 4;
  const int wq = wid & 1, wk2 = wid >> 1;

  // LDS map (bytes): Qs/Ps@0 (9216), Ks@9216, Vt@18432, RHs@27648,
  // RWs@36864, Lbuf@46080 (512). o_buf ([2][64][66] f32 = 33792) overlays
  // Ks..RWs after the main loop.
  __shared__ __align__(16) char smem[46592];
  typedef ushort_t (*arr72)[72];
  arr72 Qs  = (arr72)(smem);
  arr72 Ps  = (arr72)(smem);
  arr72 Ks  = (arr72)(smem + 9216);
  arr72 Vt  = (arr72)(smem + 18432);
  arr72 RHs = (arr72)(smem + 27648);
  arr72 RWs = (arr72)(smem + 36864);
  float* Lbuf  = (float*)(smem + 46080);   // [2][64]
  float* o_buf = (float*)(smem + 9216);    // [2][64][66]

  const int r0 = tid >> 3, c8 = (tid & 7) * 8;
#pragma unroll
  for (int h = 0; h < 2; h++) {
    const int r = r0 + h * 32;
    *(uint4*)&Qs[r][c8]  = *(const uint4*)&q_bf[(n * HWP + q0 + r) * HD + c8];
    *(uint4*)&RHs[r][c8] = *(const uint4*)&rel_h[((n * HWP + q0 + r) << 6) + c8];
    *(uint4*)&RWs[r][c8] = *(const uint4*)&rel_w[((n * HWP + q0 + r) << 6) + c8];
  }
  __syncthreads();

  // Q B-fragments (held in registers for the whole block)
  bf16x8 qb[2][2];
#pragma unroll
  for (int b = 0; b < 2; b++)
#pragma unroll
    for (int s = 0; s < 2; s++)
      qb[b][s] = *reinterpret_cast<const bf16x8*>(&Qs[wq * 32 + b * 16 + l15][s * 32 + quad * 8]);

  // K/V prefetch pointers
  const ushort_t* kp0 = k_bf + ((size_t)n * HWP + r0) * HD + c8;
  const ushort_t* kp1 = kp0 + 32 * HD;
  const ushort_t* vp0 = v_t + ((size_t)n * HD + r0) * HWP + c8;
  const ushort_t* vp1 = vp0 + 32 * HWP;
  uint4 rk0 = *(const uint4*)kp0, rk1 = *(const uint4*)kp1;
  uint4 rv0 = *(const uint4*)vp0, rv1 = *(const uint4*)vp1;

  f32x4 od[4][2];
#pragma unroll
  for (int dt = 0; dt < 4; dt++)
#pragma unroll
    for (int b = 0; b < 2; b++) od[dt][b] = (f32x4){0.f, 0.f, 0.f, 0.f};
  float l_lane[2] = {0.f, 0.f};

  for (int t = 0; t < 64; t++) {
    if (t) __syncthreads();                 // all waves done reading prev Ks/Vt
    *(uint4*)&Ks[r0][c8]      = rk0;
    *(uint4*)&Ks[r0 + 32][c8] = rk1;
    *(uint4*)&Vt[r0][c8]      = rv0;
    *(uint4*)&Vt[r0 + 32][c8] = rv1;
    __syncthreads();                        // staging visible
    if (t < 63) {                           // prefetch next tile
      const int ko = (t + 1) * 64 * HD, vo = (t + 1) * 64;
      rk0 = *(const uint4*)(kp0 + ko);
      rk1 = *(const uint4*)(kp1 + ko);
      rv0 = *(const uint4*)(vp0 + vo);
      rv1 = *(const uint4*)(vp1 + vo);
    }

    // --- S^T = K * Q^T (rows k, cols q) ---
    f32x4 sT[2][2];
#pragma unroll
    for (int a = 0; a < 2; a++)
#pragma unroll
      for (int b = 0; b < 2; b++) sT[a][b] = (f32x4){0.f, 0.f, 0.f, 0.f};
#pragma unroll
    for (int s = 0; s < 2; s++) {
      bf16x8 af0 = *reinterpret_cast<const bf16x8*>(&Ks[wk2 * 32 + l15][s * 32 + quad * 8]);
      bf16x8 af1 = *reinterpret_cast<const bf16x8*>(&Ks[wk2 * 32 + 16 + l15][s * 32 + quad * 8]);
      sT[0][0] = mfma16(af0, qb[0][s], sT[0][0]);
      sT[0][1] = mfma16(af0, qb[1][s], sT[0][1]);
      sT[1][0] = mfma16(af1, qb[0][s], sT[1][0]);
      sT[1][1] = mfma16(af1, qb[1][s], sT[1][1]);
    }

    // --- bias + exp2 + P quadrant write (wave-local) ---
    float rw[2][4];
#pragma unroll
    for (int a = 0; a < 2; a++) {
      uint2 u = *(const uint2*)&RWs[t][wk2 * 32 + a * 16 + quad * 4];
      rw[a][0] = __uint_as_float(u.x << 16);
      rw[a][1] = __uint_as_float(u.x & 0xffff0000u);
      rw[a][2] = __uint_as_float(u.y << 16);
      rw[a][3] = __uint_as_float(u.y & 0xffff0000u);
    }
#pragma unroll
    for (int b = 0; b < 2; b++) {
      const float rhf = bf2f(RHs[wq * 32 + b * 16 + l15][t]);
#pragma unroll
      for (int a = 0; a < 2; a++) {
        float p0 = EXP2(sT[a][b][0] + rhf + rw[a][0]);
        float p1 = EXP2(sT[a][b][1] + rhf + rw[a][1]);
        float p2 = EXP2(sT[a][b][2] + rhf + rw[a][2]);
        float p3 = EXP2(sT[a][b][3] + rhf + rw[a][3]);
        l_lane[b] += (p0 + p1) + (p2 + p3);
        uint2 w2; w2.x = packbf(p0, p1); w2.y = packbf(p2, p3);
        *(uint2*)&Ps[wq * 32 + b * 16 + l15][wk2 * 32 + a * 16 + quad * 4] = w2;
      }
    }

    // --- o^T += V^T * P^T (own quadrant; k-range = this wave's key half) ---
    bf16x8 pf0 = *reinterpret_cast<const bf16x8*>(&Ps[wq * 32 + l15][wk2 * 32 + quad * 8]);
    bf16x8 pf1 = *reinterpret_cast<const bf16x8*>(&Ps[wq * 32 + 16 + l15][wk2 * 32 + quad * 8]);
#pragma unroll
    for (int dt = 0; dt < 4; dt++) {
      bf16x8 vf = *reinterpret_cast<const bf16x8*>(&Vt[dt * 16 + l15][wk2 * 32 + quad * 8]);
      od[dt][0] = mfma16(vf, pf0, od[dt][0]);
      od[dt][1] = mfma16(vf, pf1, od[dt][1]);
    }
  }

  // --- combine: l across quads (shfl) then across wk2 (LDS) ---
#pragma unroll
  for (int b = 0; b < 2; b++) {
    l_lane[b] += __shfl_xor(l_lane[b], 16, 64);
    l_lane[b] += __shfl_xor(l_lane[b], 32, 64);
  }
  __syncthreads();                          // tile-63 reads done before overlay
  if (lane < 16) {
#pragma unroll
    for (int b = 0; b < 2; b++)
      Lbuf[wk2 * 64 + wq * 32 + b * 16 + lane] = l_lane[b];
  }
#pragma unroll
  for (int dt = 0; dt < 4; dt++)
#pragma unroll
    for (int b = 0; b < 2; b++)
#pragma unroll
      for (int r = 0; r < 4; r++)
        o_buf[wk2 * 64 * 66 + (dt * 16 + quad * 4 + r) * 66 + (wq * 32 + b * 16 + l15)] =
            od[dt][b][r];
  __syncthreads();

  // --- cooperative epilogue: o = (part0+part1)/l, bf16, coalesced store ---
  {
    const int q = tid >> 2, db = (tid & 3) * 16;
    const float linv = 1.0f / (Lbuf[q] + Lbuf[64 + q]);
    unsigned outd[8];
#pragma unroll
    for (int j = 0; j < 8; j++) {
      const int d0 = db + 2 * j;
      const float v0 = (o_buf[d0 * 66 + q] + o_buf[64 * 66 + d0 * 66 + q]) * linv;
      const float v1 = (o_buf[(d0 + 1) * 66 + q] + o_buf[64 * 66 + (d0 + 1) * 66 + q]) * linv;
      outd[j] = (unsigned)f2bf(v0) | ((unsigned)f2bf(v1) << 16);
    }
    uint4 s0 = make_uint4(outd[0], outd[1], outd[2], outd[3]);
    uint4 s1 = make_uint4(outd[4], outd[5], outd[6], outd[7]);
    *(uint4*)&ao_bf[(size_t)(q0 + q) * 768 + n * 64 + db]     = s0;
    *(uint4*)&ao_bf[(size_t)(q0 + q) * 768 + n * 64 + db + 8] = s1;
  }
}

// ---------------------------------------------------------------------------
__global__ __launch_bounds__(256) void proj_gemm(
    const ushort_t* __restrict__ ao_bf, const ushort_t* __restrict__ pw_bf,
    const float* __restrict__ pb, float* __restrict__ out) {
  __shared__ ushort_t As[128][40];
  __shared__ ushort_t Bs[128][40];
  const int m0 = blockIdx.x * 128, n0 = blockIdx.y * 128;
  const int tid = threadIdx.x;
  const int lane = tid & 63, wid = tid >> 6;
  const int l15 = lane & 15, quad = lane >> 4;
  const int wm = (wid >> 1) * 64, wn = (wid & 1) * 64;

  f32x4 acc[4][4];
#pragma unroll
  for (int a = 0; a < 4; a++)
#pragma unroll
    for (int b = 0; b < 4; b++) acc[a][b] = (f32x4){0.f, 0.f, 0.f, 0.f};

  const int sr = tid >> 2;
  const int sc = (tid & 3) * 8;
  for (int kt = 0; kt < 24; kt++) {
#pragma unroll
    for (int h = 0; h < 2; h++) {
      int row = sr + h * 64;
      *(uint4*)&As[row][sc] = *(const uint4*)&ao_bf[(m0 + row) * CIN + kt * 32 + sc];
      *(uint4*)&Bs[row][sc] = *(const uint4*)&pw_bf[(n0 + row) * CIN + kt * 32 + sc];
    }
    __syncthreads();
    bf16x8 af[4], bfr[4];
#pragma unroll
    for (int mb = 0; mb < 4; mb++)
      af[mb] = *reinterpret_cast<const bf16x8*>(&As[wm + mb * 16 + l15][quad * 8]);
#pragma unroll
    for (int nb = 0; nb < 4; nb++)
      bfr[nb] = *reinterpret_cast<const bf16x8*>(&Bs[wn + nb * 16 + l15][quad * 8]);
#pragma unroll
    for (int mb = 0; mb < 4; mb++)
#pragma unroll
      for (int nb = 0; nb < 4; nb++)
        acc[mb][nb] = mfma16(af[mb], bfr[nb], acc[mb][nb]);
    __syncthreads();
  }

#pragma unroll
  for (int mb = 0; mb < 4; mb++) {
#pragma unroll
    for (int nb = 0; nb < 4; nb++) {
      const int colg = n0 + wn + nb * 16 + l15;
      const float bias = pb[colg];
#pragma unroll
      for (int r = 0; r < 4; r++) {
        const int rowg = m0 + wm + mb * 16 + quad * 4 + r;
        out[rowg * 768 + colg] = acc[mb][nb][r] + bias;
      }
    }
  }
}

// ---------------------------------------------------------------------------
extern "C" void kernel_launch(void* const* d_in, const int* in_sizes, int n_in,
                              void* d_out, int out_size, void* d_ws, size_t ws_size,
                              hipStream_t stream) {
  (void)in_sizes; (void)n_in; (void)out_size; (void)ws_size;
  const float* x   = (const float*)d_in[0];
  const float* wq  = (const float*)d_in[1];
  const float* bq  = (const float*)d_in[2];
  const float* wk  = (const float*)d_in[3];
  const float* bk  = (const float*)d_in[4];
  const float* wv  = (const float*)d_in[5];
  const float* bv  = (const float*)d_in[6];
  const float* rph = (const float*)d_in[7];
  const float* rpw = (const float*)d_in[8];
  const float* pw  = (const float*)d_in[9];
  const float* pb  = (const float*)d_in[10];
  float* out = (float*)d_out;

  char* ws = (char*)d_ws;
  size_t off = 0;
  auto alloc = [&](size_t bytes) -> char* {
    char* p = ws + off;
    off += (bytes + 255) & ~(size_t)255;
    return p;
  };
  ushort_t* x_bf   = (ushort_t*)alloc((size_t)HWP * CIN * 2);
  ushort_t* w_bf   = (ushort_t*)alloc((size_t)3 * NHD * HD * CIN * 2);
  ushort_t* pw_bf  = (ushort_t*)alloc((size_t)NHD * HD * CIN * 2);
  ushort_t* rph_bf = (ushort_t*)alloc((size_t)127 * HD * 2);
  ushort_t* rpw_bf = (ushort_t*)alloc((size_t)127 * HD * 2);
  float*    bias_all = (float*)alloc((size_t)3 * NHD * HD * 4);
  ushort_t* q_bf  = (ushort_t*)alloc((size_t)NHD * HWP * HD * 2);
  ushort_t* k_bf  = (ushort_t*)alloc((size_t)NHD * HWP * HD * 2);
  ushort_t* v_t   = (ushort_t*)alloc((size_t)NHD * HWP * HD * 2);
  ushort_t* rel_h = (ushort_t*)alloc((size_t)NHD * HWP * 64 * 2);
  ushort_t* rel_w = (ushort_t*)alloc((size_t)NHD * HWP * 64 * 2);
  ushort_t* ao_bf = (ushort_t*)alloc((size_t)HWP * CIN * 2);

  convert_kernel<<<dim3(2048), dim3(256), 0, stream>>>(
      x, wq, bq, wk, bk, wv, bv, rph, rpw, pw,
      x_bf, w_bf, pw_bf, rph_bf, rpw_bf, bias_all);
  qkv_gemm<<<dim3(32, 18), dim3(256), 0, stream>>>(
      x_bf, w_bf, bias_all, q_bf, k_bf, v_t);
  rel_kernel<<<dim3(NHD * 64, 2), dim3(256), 0, stream>>>(
      q_bf, rph_bf, rpw_bf, rel_h, rel_w);
  flash_kernel<<<dim3(NHD * 64), dim3(256), 0, stream>>>(
      q_bf, k_bf, v_t, rel_h, rel_w, ao_bf);
  proj_gemm<<<dim3(32, 6), dim3(256), 0, stream>>>(ao_bf, pw_bf, pb, out);
}

// Round 4
// 241.230 us; speedup vs baseline: 1.5051x; 1.0524x over previous
//
#include <hip/hip_runtime.h>
#include <stdint.h>

// ---------------------------------------------------------------------------
// SAM encoder attention, MI355X/gfx950.
// convert(fp32->bf16, q pre-scaled by scale*log2e) -> qkv_gemm (glds staging)
// -> rel_kernel (rel_hT transposed, rel_w standard; *8 => *log2e) ->
// flash (S^T/o^T, no-max exp2 softmax, global_load_lds K/V staging with XOR
// bank swizzle, 4 blocks/CU) -> proj_gemm.
// MFMA 16x16x32 bf16; layouts per verified m89/m120 mappings:
//   A/B: m(n)=lane&15, k=quad*8+j ; C/D: col=lane&15, row=quad*4+reg.
// ---------------------------------------------------------------------------

typedef unsigned short ushort_t;
typedef __attribute__((ext_vector_type(8))) __bf16 bf16x8;
typedef __attribute__((ext_vector_type(4))) float f32x4;

#define NHD 12
#define HD 64
#define CIN 768
#define HWP 4096
#define QPRE 0.18033688f   /* 0.125 * log2(e) */

#if __has_builtin(__builtin_amdgcn_exp2f)
#define EXP2(x) __builtin_amdgcn_exp2f(x)
#else
#define EXP2(x) exp2f(x)
#endif

__device__ __forceinline__ ushort_t f2bf(float f) {
  union { float f; unsigned u; } v; v.f = f;
  unsigned r = (v.u + 0x7fffu + ((v.u >> 16) & 1u)) >> 16;  // RNE
  return (ushort_t)r;
}
__device__ __forceinline__ float bf2f(ushort_t h) {
  union { unsigned u; float f; } v; v.u = ((unsigned)h) << 16;
  return v.f;
}
__device__ __forceinline__ unsigned packbf(float a, float b) {
  unsigned ua = (__float_as_uint(a) + 0x8000u) >> 16;
  unsigned ub = (__float_as_uint(b) + 0x8000u) & 0xffff0000u;
  return ua | ub;
}
__device__ __forceinline__ f32x4 mfma16(bf16x8 a, bf16x8 b, f32x4 c) {
  return __builtin_amdgcn_mfma_f32_16x16x32_bf16(a, b, c, 0, 0, 0);
}

// async global->LDS, 16B per lane. LDS dest = wave-uniform base + lane*16.
typedef const __attribute__((address_space(1))) unsigned int* gas_u32p;
typedef __attribute__((address_space(3))) unsigned int* las_u32p;
__device__ __forceinline__ void glds16(const ushort_t* g, ushort_t* l) {
  __builtin_amdgcn_global_load_lds((gas_u32p)g, (las_u32p)l, 16, 0, 0);
}

// ---------------------------------------------------------------------------
// fp32 -> bf16 conversions, vectorized (16B load / 8B store per lane).
// ---------------------------------------------------------------------------
__global__ void convert_kernel(const float* __restrict__ x,
                               const float* __restrict__ wq, const float* __restrict__ bq,
                               const float* __restrict__ wk, const float* __restrict__ bk,
                               const float* __restrict__ wv, const float* __restrict__ bv,
                               const float* __restrict__ rph, const float* __restrict__ rpw,
                               const float* __restrict__ pw,
                               ushort_t* __restrict__ x_bf, ushort_t* __restrict__ w_bf,
                               ushort_t* __restrict__ pw_bf, ushort_t* __restrict__ rph_bf,
                               ushort_t* __restrict__ rpw_bf, float* __restrict__ bias_all) {
  const int i = blockIdx.x * blockDim.x + threadIdx.x;
  const int stride = gridDim.x * blockDim.x;
  const int NX4 = (HWP * CIN) / 4;
  const int NW4 = (NHD * HD * CIN) / 4;
  const int NR4 = (127 * HD) / 4;
  for (int t = i; t < NX4; t += stride) {
    float4 a = ((const float4*)x)[t];
    uint2 o; o.x = packbf(a.x, a.y); o.y = packbf(a.z, a.w);
    ((uint2*)x_bf)[t] = o;
  }
  for (int t = i; t < NW4; t += stride) {
    float4 a = ((const float4*)wq)[t];
    float4 b = ((const float4*)wk)[t];
    float4 c = ((const float4*)wv)[t];
    float4 d = ((const float4*)pw)[t];
    uint2 o;
    o.x = packbf(a.x, a.y); o.y = packbf(a.z, a.w); ((uint2*)w_bf)[t] = o;
    o.x = packbf(b.x, b.y); o.y = packbf(b.z, b.w); ((uint2*)w_bf)[NW4 + t] = o;
    o.x = packbf(c.x, c.y); o.y = packbf(c.z, c.w); ((uint2*)w_bf)[2 * NW4 + t] = o;
    o.x = packbf(d.x, d.y); o.y = packbf(d.z, d.w); ((uint2*)pw_bf)[t] = o;
  }
  for (int t = i; t < NR4; t += stride) {
    float4 a = ((const float4*)rph)[t];
    float4 b = ((const float4*)rpw)[t];
    uint2 o;
    o.x = packbf(a.x, a.y); o.y = packbf(a.z, a.w); ((uint2*)rph_bf)[t] = o;
    o.x = packbf(b.x, b.y); o.y = packbf(b.z, b.w); ((uint2*)rpw_bf)[t] = o;
  }
  for (int t = i; t < NHD * HD; t += stride) {
    bias_all[t]        = bq[t];
    bias_all[768 + t]  = bk[t];
    bias_all[1536 + t] = bv[t];
  }
}

// ---------------------------------------------------------------------------
// QKV GEMM: C(4096x2304) = X * W^T, glds staging, XOR-swizzled [128][32] LDS
// (64B rows, cg^((row>>1)&3) => 2-way bank aliasing only).
// q stored pre-scaled by QPRE; v packed 8B stores to [n][d][p].
// ---------------------------------------------------------------------------
__global__ __launch_bounds__(256) void qkv_gemm(
    const ushort_t* __restrict__ x_bf, const ushort_t* __restrict__ w_bf,
    const float* __restrict__ bias_all,
    ushort_t* __restrict__ q_bf, ushort_t* __restrict__ k_bf, ushort_t* __restrict__ v_t) {
  __shared__ ushort_t As[128 * 32];
  __shared__ ushort_t Bs[128 * 32];
  const int m0 = blockIdx.x * 128, n0 = blockIdx.y * 128;
  const int tid = threadIdx.x;
  const int lane = tid & 63, wid = tid >> 6;
  const int l15 = lane & 15, quad = lane >> 4;
  const int wm = (wid >> 1) * 64, wn = (wid & 1) * 64;
  const int gr = lane >> 2;                        // row within 16-row group
  const int cl = (lane & 3) ^ ((lane >> 3) & 3);   // swizzled src col group
  const int swz = quad ^ ((l15 >> 1) & 3);         // swizzled read col group
  const int Ra = wid * 16;

  f32x4 acc[4][4];
#pragma unroll
  for (int a = 0; a < 4; a++)
#pragma unroll
    for (int b = 0; b < 4; b++) acc[a][b] = (f32x4){0.f, 0.f, 0.f, 0.f};

  for (int kt = 0; kt < 24; kt++) {
    __syncthreads();   // prev-iter frag reads done
    const size_t kofs = (size_t)kt * 32 + cl * 8;
    glds16(&x_bf[(size_t)(m0 + Ra + gr) * CIN + kofs],      &As[Ra * 32]);
    glds16(&x_bf[(size_t)(m0 + 64 + Ra + gr) * CIN + kofs], &As[(64 + Ra) * 32]);
    glds16(&w_bf[(size_t)(n0 + Ra + gr) * CIN + kofs],      &Bs[Ra * 32]);
    glds16(&w_bf[(size_t)(n0 + 64 + Ra + gr) * CIN + kofs], &Bs[(64 + Ra) * 32]);
    __syncthreads();   // DMA complete (vmcnt drained at barrier)
    bf16x8 af[4], bfr[4];
#pragma unroll
    for (int mb = 0; mb < 4; mb++)
      af[mb] = *reinterpret_cast<const bf16x8*>(&As[(wm + mb * 16 + l15) * 32 + swz * 8]);
#pragma unroll
    for (int nb = 0; nb < 4; nb++)
      bfr[nb] = *reinterpret_cast<const bf16x8*>(&Bs[(wn + nb * 16 + l15) * 32 + swz * 8]);
#pragma unroll
    for (int mb = 0; mb < 4; mb++)
#pragma unroll
      for (int nb = 0; nb < 4; nb++)
        acc[mb][nb] = mfma16(af[mb], bfr[nb], acc[mb][nb]);
  }

#pragma unroll
  for (int mb = 0; mb < 4; mb++) {
#pragma unroll
    for (int nb = 0; nb < 4; nb++) {
      const int colg = n0 + wn + nb * 16 + l15;
      const float bias = bias_all[colg];
      if (colg >= 1536) {
        const int j = colg - 1536;   // n*64+d
        uint2 wv2;
        wv2.x = packbf(acc[mb][nb][0] + bias, acc[mb][nb][1] + bias);
        wv2.y = packbf(acc[mb][nb][2] + bias, acc[mb][nb][3] + bias);
        *(uint2*)&v_t[(size_t)j * HWP + m0 + wm + mb * 16 + quad * 4] = wv2;
      } else {
#pragma unroll
        for (int r = 0; r < 4; r++) {
          const int rowg = m0 + wm + mb * 16 + quad * 4 + r;
          const float val = acc[mb][nb][r] + bias;
          if (colg < 768) {
            q_bf[(((size_t)(colg >> 6)) * HWP + rowg) * HD + (colg & 63)] = f2bf(val * QPRE);
          } else {
            const int j = colg - 768;
            k_bf[(((size_t)(j >> 6)) * HWP + rowg) * HD + (j & 63)] = f2bf(val);
          }
        }
      }
    }
  }
}

// ---------------------------------------------------------------------------
// rel tables. mode 0 -> rel_hT[n][h][t][w] (transposed, packed 8B stores);
// mode 1 -> rel_w[n][p][w2] (standard). Outputs *8 => rel * log2(e)
// (q_bf pre-scaled by QPRE = scale*log2e).
// ---------------------------------------------------------------------------
__global__ __launch_bounds__(256) void rel_kernel(
    const ushort_t* __restrict__ q_bf, const ushort_t* __restrict__ rph_bf,
    const ushort_t* __restrict__ rpw_bf,
    ushort_t* __restrict__ rel_hT, ushort_t* __restrict__ rel_w) {
  const int mode = blockIdx.y;
  const ushort_t* __restrict__ rp_bf = mode ? rpw_bf : rph_bf;
  const int bx = blockIdx.x;
  const int n = bx >> 6, hw = bx & 63;
  const int tid = threadIdx.x;
  const int lane = tid & 63, wid = tid >> 6;
  const int l15 = lane & 15, quad = lane >> 4;

  __shared__ ushort_t Qs[64][72];
  __shared__ ushort_t Rs[64][72];

  const int r0 = tid >> 3, c8 = (tid & 7) * 8;
#pragma unroll
  for (int h = 0; h < 2; h++) {
    const int r = r0 + h * 32;
    const int p = (mode == 0) ? (hw * 64 + r) : (r * 64 + hw);
    *(uint4*)&Qs[r][c8] = *(const uint4*)&q_bf[((size_t)n * HWP + p) * HD + c8];
    *(uint4*)&Rs[r][c8] = *(const uint4*)&rp_bf[(63 + hw - r) * HD + c8];
  }
  __syncthreads();

  bf16x8 a0 = *reinterpret_cast<const bf16x8*>(&Qs[wid * 16 + l15][quad * 8]);
  bf16x8 a1 = *reinterpret_cast<const bf16x8*>(&Qs[wid * 16 + l15][32 + quad * 8]);
#pragma unroll
  for (int nb = 0; nb < 4; nb++) {
    bf16x8 b0 = *reinterpret_cast<const bf16x8*>(&Rs[nb * 16 + l15][quad * 8]);
    bf16x8 b1 = *reinterpret_cast<const bf16x8*>(&Rs[nb * 16 + l15][32 + quad * 8]);
    f32x4 c = (f32x4){0.f, 0.f, 0.f, 0.f};
    c = mfma16(a0, b0, c);
    c = mfma16(a1, b1, c);
    const int col = nb * 16 + l15;
    if (mode == 0) {
      // rel_hT[((n*64+hw)*64 + t=col)*64 + w], w = wid*16+quad*4+r (packed)
      uint2 o;
      o.x = packbf(c[0] * 8.0f, c[1] * 8.0f);
      o.y = packbf(c[2] * 8.0f, c[3] * 8.0f);
      *(uint2*)&rel_hT[(((size_t)(n * 64 + hw) * 64) + col) * 64 + wid * 16 + quad * 4] = o;
    } else {
#pragma unroll
      for (int r = 0; r < 4; r++) {
        const int lr = wid * 16 + quad * 4 + r;
        const int p2 = lr * 64 + hw;
        rel_w[((size_t)n * HWP + p2) * 64 + col] = f2bf(c[r] * 8.0f);
      }
    }
  }
}

// ---------------------------------------------------------------------------
// Flash attention, S^T/o^T scheme. Block = (head n, q-row qt); 4 waves 2x2
// (wq = q-half, wk2 = key-half). K/V staged via global_load_lds into
// XOR-swizzled [64][64] tiles (cg ^ (row&7) => 2-way aliasing only); DMA for
// tile t+1 issued right after the read-barrier, overlapping all compute.
// rel_hT read from global (2 scalars/lane/tile, prefetched). LDS 34.3 KB ->
// 4 blocks/CU. No-max softmax in exp2 domain; o accumulates in MFMA C regs.
// ---------------------------------------------------------------------------
__global__ __launch_bounds__(256, 4) void flash_kernel(
    const ushort_t* __restrict__ q_bf, const ushort_t* __restrict__ k_bf,
    const ushort_t* __restrict__ v_t, const ushort_t* __restrict__ rel_hT,
    const ushort_t* __restrict__ rel_w, ushort_t* __restrict__ ao_bf) {
  const int bx = blockIdx.x;
  const int n = bx >> 6, qt = bx & 63;
  const int q0 = qt * 64;
  const int tid = threadIdx.x;
  const int lane = tid & 63, wid = tid >> 6;
  const int l15 = lane & 15, quad = lane >> 4;
  const int wq = wid & 1, wk2 = wid >> 1;

  // LDS: Ks@0 [64][64], Vt@8192 [64][64], Ps/Qs@16384 [64][72],
  // RWs@25600 [64][64], Lbuf@33792 [2][64]. o_buf [2][64][66] f32 overlays
  // [0,33792) in the epilogue.
  __shared__ __align__(16) char smem[34304];
  ushort_t* KsF  = (ushort_t*)smem;
  ushort_t* VtF  = (ushort_t*)(smem + 8192);
  ushort_t* PsF  = (ushort_t*)(smem + 16384);
  ushort_t* RWsF = (ushort_t*)(smem + 25600);
  float* o_buf = (float*)smem;
  float* Lbuf  = (float*)(smem + 33792);

  const int r0 = tid >> 3, c8 = (tid & 7) * 8;
#pragma unroll
  for (int h = 0; h < 2; h++) {
    const int r = r0 + h * 32;
    *(uint4*)&PsF[r * 72 + c8]  = *(const uint4*)&q_bf[((size_t)n * HWP + q0 + r) * HD + c8];
    *(uint4*)&RWsF[r * 64 + c8] = *(const uint4*)&rel_w[(((size_t)n * HWP + q0 + r) << 6) + c8];
  }
  __syncthreads();

  bf16x8 qb[2][2];
#pragma unroll
  for (int b = 0; b < 2; b++)
#pragma unroll
    for (int s = 0; s < 2; s++)
      qb[b][s] = *reinterpret_cast<const bf16x8*>(&PsF[(wq * 32 + b * 16 + l15) * 72 + s * 32 + quad * 8]);

  const int gr8 = lane >> 3;
  const int cl8 = (lane & 7) ^ ((lane >> 3) & 7);  // swizzled src col group
  const int rsw = l15 & 7;                         // read-side row swizzle key

  auto stageKV = [&](int tt) {
    const size_t kbase = ((size_t)n * HWP + (size_t)tt * 64 + gr8) * HD + cl8 * 8;
#pragma unroll
    for (int i = 0; i < 2; i++) {
      const int R0 = wid * 16 + i * 8;
      glds16(&k_bf[kbase + (size_t)R0 * HD], &KsF[R0 * 64]);
    }
    const size_t vbase = ((size_t)n * HD + gr8) * HWP + (size_t)tt * 64 + cl8 * 8;
#pragma unroll
    for (int i = 0; i < 2; i++) {
      const int R0 = wid * 16 + i * 8;
      glds16(&v_t[vbase + (size_t)R0 * HWP], &VtF[R0 * 64]);
    }
  };

  stageKV(0);

  // rel_hT prefetch (2 scalars/lane/tile)
  const ushort_t* rhbase = rel_hT + (((size_t)n * 64 + qt) << 12);
  ushort_t rhreg[2];
  rhreg[0] = rhbase[wq * 32 + l15];
  rhreg[1] = rhbase[wq * 32 + 16 + l15];

  f32x4 od[4][2];
#pragma unroll
  for (int dt = 0; dt < 4; dt++)
#pragma unroll
    for (int b = 0; b < 2; b++) od[dt][b] = (f32x4){0.f, 0.f, 0.f, 0.f};
  float l_lane[2] = {0.f, 0.f};

  for (int t = 0; t < 64; t++) {
    __syncthreads();   // B1: DMA(t) complete everywhere (vmcnt drained)

    bf16x8 af[2][2], vf[4];
#pragma unroll
    for (int a = 0; a < 2; a++)
#pragma unroll
      for (int s = 0; s < 2; s++)
        af[a][s] = *reinterpret_cast<const bf16x8*>(
            &KsF[(wk2 * 32 + a * 16 + l15) * 64 + ((s * 4 + quad) ^ rsw) * 8]);
#pragma unroll
    for (int dt = 0; dt < 4; dt++)
      vf[dt] = *reinterpret_cast<const bf16x8*>(
          &VtF[(dt * 16 + l15) * 64 + ((wk2 * 4 + quad) ^ rsw) * 8]);

    __syncthreads();   // B2: all Ks/Vt reads done
    if (t < 63) stageKV(t + 1);   // DMA overlaps S^T + exp + PV

    // --- S^T = K * Q^T ---
    f32x4 sT[2][2];
#pragma unroll
    for (int a = 0; a < 2; a++)
#pragma unroll
      for (int b = 0; b < 2; b++) sT[a][b] = (f32x4){0.f, 0.f, 0.f, 0.f};
#pragma unroll
    for (int s = 0; s < 2; s++) {
      sT[0][0] = mfma16(af[0][s], qb[0][s], sT[0][0]);
      sT[0][1] = mfma16(af[0][s], qb[1][s], sT[0][1]);
      sT[1][0] = mfma16(af[1][s], qb[0][s], sT[1][0]);
      sT[1][1] = mfma16(af[1][s], qb[1][s], sT[1][1]);
    }

    float rw[2][4];
#pragma unroll
    for (int a = 0; a < 2; a++) {
      uint2 u = *(const uint2*)&RWsF[t * 64 + wk2 * 32 + a * 16 + quad * 4];
      rw[a][0] = __uint_as_float(u.x << 16);
      rw[a][1] = __uint_as_float(u.x & 0xffff0000u);
      rw[a][2] = __uint_as_float(u.y << 16);
      rw[a][3] = __uint_as_float(u.y & 0xffff0000u);
    }
    float rhf[2] = {bf2f(rhreg[0]), bf2f(rhreg[1])};
    if (t < 63) {
      rhreg[0] = rhbase[(t + 1) * 64 + wq * 32 + l15];
      rhreg[1] = rhbase[(t + 1) * 64 + wq * 32 + 16 + l15];
    }

#pragma unroll
    for (int b = 0; b < 2; b++) {
#pragma unroll
      for (int a = 0; a < 2; a++) {
        float p0 = EXP2(sT[a][b][0] + rhf[b] + rw[a][0]);
        float p1 = EXP2(sT[a][b][1] + rhf[b] + rw[a][1]);
        float p2 = EXP2(sT[a][b][2] + rhf[b] + rw[a][2]);
        float p3 = EXP2(sT[a][b][3] + rhf[b] + rw[a][3]);
        l_lane[b] += (p0 + p1) + (p2 + p3);
        uint2 w2; w2.x = packbf(p0, p1); w2.y = packbf(p2, p3);
        *(uint2*)&PsF[(wq * 32 + b * 16 + l15) * 72 + wk2 * 32 + a * 16 + quad * 4] = w2;
      }
    }

    // --- o^T += V^T * P^T (own quadrant, wave-local) ---
    bf16x8 pf0 = *reinterpret_cast<const bf16x8*>(&PsF[(wq * 32 + l15) * 72 + wk2 * 32 + quad * 8]);
    bf16x8 pf1 = *reinterpret_cast<const bf16x8*>(&PsF[(wq * 32 + 16 + l15) * 72 + wk2 * 32 + quad * 8]);
#pragma unroll
    for (int dt = 0; dt < 4; dt++) {
      od[dt][0] = mfma16(vf[dt], pf0, od[dt][0]);
      od[dt][1] = mfma16(vf[dt], pf1, od[dt][1]);
    }
  }

  // --- combine l across quads, then across wk2 via LDS ---
#pragma unroll
  for (int b = 0; b < 2; b++) {
    l_lane[b] += __shfl_xor(l_lane[b], 16, 64);
    l_lane[b] += __shfl_xor(l_lane[b], 32, 64);
  }
  __syncthreads();   // all waves done with Ks/Vt/Ps before overlay
  if (lane < 16) {
#pragma unroll
    for (int b = 0; b < 2; b++)
      Lbuf[wk2 * 64 + wq * 32 + b * 16 + lane] = l_lane[b];
  }
#pragma unroll
  for (int dt = 0; dt < 4; dt++)
#pragma unroll
    for (int b = 0; b < 2; b++)
#pragma unroll
      for (int r = 0; r < 4; r++)
        o_buf[wk2 * 64 * 66 + (dt * 16 + quad * 4 + r) * 66 + (wq * 32 + b * 16 + l15)] =
            od[dt][b][r];
  __syncthreads();

  // --- cooperative epilogue: o = (part0+part1)/l, coalesced bf16 stores ---
  {
    const int q = tid >> 2, db = (tid & 3) * 16;
    const float linv = 1.0f / (Lbuf[q] + Lbuf[64 + q]);
    unsigned outd[8];
#pragma unroll
    for (int j = 0; j < 8; j++) {
      const int d0 = db + 2 * j;
      const float v0 = (o_buf[d0 * 66 + q] + o_buf[64 * 66 + d0 * 66 + q]) * linv;
      const float v1 = (o_buf[(d0 + 1) * 66 + q] + o_buf[64 * 66 + (d0 + 1) * 66 + q]) * linv;
      outd[j] = (unsigned)f2bf(v0) | ((unsigned)f2bf(v1) << 16);
    }
    uint4 s0 = make_uint4(outd[0], outd[1], outd[2], outd[3]);
    uint4 s1 = make_uint4(outd[4], outd[5], outd[6], outd[7]);
    *(uint4*)&ao_bf[(size_t)(q0 + q) * 768 + n * 64 + db]     = s0;
    *(uint4*)&ao_bf[(size_t)(q0 + q) * 768 + n * 64 + db + 8] = s1;
  }
}

// ---------------------------------------------------------------------------
// Output projection, same glds/swizzle structure, fp32 out.
// ---------------------------------------------------------------------------
__global__ __launch_bounds__(256) void proj_gemm(
    const ushort_t* __restrict__ ao_bf, const ushort_t* __restrict__ pw_bf,
    const float* __restrict__ pb, float* __restrict__ out) {
  __shared__ ushort_t As[128 * 32];
  __shared__ ushort_t Bs[128 * 32];
  const int m0 = blockIdx.x * 128, n0 = blockIdx.y * 128;
  const int tid = threadIdx.x;
  const int lane = tid & 63, wid = tid >> 6;
  const int l15 = lane & 15, quad = lane >> 4;
  const int wm = (wid >> 1) * 64, wn = (wid & 1) * 64;
  const int gr = lane >> 2;
  const int cl = (lane & 3) ^ ((lane >> 3) & 3);
  const int swz = quad ^ ((l15 >> 1) & 3);
  const int Ra = wid * 16;

  f32x4 acc[4][4];
#pragma unroll
  for (int a = 0; a < 4; a++)
#pragma unroll
    for (int b = 0; b < 4; b++) acc[a][b] = (f32x4){0.f, 0.f, 0.f, 0.f};

  for (int kt = 0; kt < 24; kt++) {
    __syncthreads();
    const size_t kofs = (size_t)kt * 32 + cl * 8;
    glds16(&ao_bf[(size_t)(m0 + Ra + gr) * CIN + kofs],      &As[Ra * 32]);
    glds16(&ao_bf[(size_t)(m0 + 64 + Ra + gr) * CIN + kofs], &As[(64 + Ra) * 32]);
    glds16(&pw_bf[(size_t)(n0 + Ra + gr) * CIN + kofs],      &Bs[Ra * 32]);
    glds16(&pw_bf[(size_t)(n0 + 64 + Ra + gr) * CIN + kofs], &Bs[(64 + Ra) * 32]);
    __syncthreads();
    bf16x8 af[4], bfr[4];
#pragma unroll
    for (int mb = 0; mb < 4; mb++)
      af[mb] = *reinterpret_cast<const bf16x8*>(&As[(wm + mb * 16 + l15) * 32 + swz * 8]);
#pragma unroll
    for (int nb = 0; nb < 4; nb++)
      bfr[nb] = *reinterpret_cast<const bf16x8*>(&Bs[(wn + nb * 16 + l15) * 32 + swz * 8]);
#pragma unroll
    for (int mb = 0; mb < 4; mb++)
#pragma unroll
      for (int nb = 0; nb < 4; nb++)
        acc[mb][nb] = mfma16(af[mb], bfr[nb], acc[mb][nb]);
  }

#pragma unroll
  for (int mb = 0; mb < 4; mb++) {
#pragma unroll
    for (int nb = 0; nb < 4; nb++) {
      const int colg = n0 + wn + nb * 16 + l15;
      const float bias = pb[colg];
#pragma unroll
      for (int r = 0; r < 4; r++) {
        const int rowg = m0 + wm + mb * 16 + quad * 4 + r;
        out[(size_t)rowg * 768 + colg] = acc[mb][nb][r] + bias;
      }
    }
  }
}

// ---------------------------------------------------------------------------
extern "C" void kernel_launch(void* const* d_in, const int* in_sizes, int n_in,
                              void* d_out, int out_size, void* d_ws, size_t ws_size,
                              hipStream_t stream) {
  (void)in_sizes; (void)n_in; (void)out_size; (void)ws_size;
  const float* x   = (const float*)d_in[0];
  const float* wq  = (const float*)d_in[1];
  const float* bq  = (const float*)d_in[2];
  const float* wk  = (const float*)d_in[3];
  const float* bk  = (const float*)d_in[4];
  const float* wv  = (const float*)d_in[5];
  const float* bv  = (const float*)d_in[6];
  const float* rph = (const float*)d_in[7];
  const float* rpw = (const float*)d_in[8];
  const float* pw  = (const float*)d_in[9];
  const float* pb  = (const float*)d_in[10];
  float* out = (float*)d_out;

  char* ws = (char*)d_ws;
  size_t off = 0;
  auto alloc = [&](size_t bytes) -> char* {
    char* p = ws + off;
    off += (bytes + 255) & ~(size_t)255;
    return p;
  };
  ushort_t* x_bf   = (ushort_t*)alloc((size_t)HWP * CIN * 2);
  ushort_t* w_bf   = (ushort_t*)alloc((size_t)3 * NHD * HD * CIN * 2);
  ushort_t* pw_bf  = (ushort_t*)alloc((size_t)NHD * HD * CIN * 2);
  ushort_t* rph_bf = (ushort_t*)alloc((size_t)127 * HD * 2);
  ushort_t* rpw_bf = (ushort_t*)alloc((size_t)127 * HD * 2);
  float*    bias_all = (float*)alloc((size_t)3 * NHD * HD * 4);
  ushort_t* q_bf   = (ushort_t*)alloc((size_t)NHD * HWP * HD * 2);
  ushort_t* k_bf   = (ushort_t*)alloc((size_t)NHD * HWP * HD * 2);
  ushort_t* v_t    = (ushort_t*)alloc((size_t)NHD * HWP * HD * 2);
  ushort_t* rel_hT = (ushort_t*)alloc((size_t)NHD * HWP * 64 * 2);
  ushort_t* rel_w  = (ushort_t*)alloc((size_t)NHD * HWP * 64 * 2);
  ushort_t* ao_bf  = (ushort_t*)alloc((size_t)HWP * CIN * 2);

  convert_kernel<<<dim3(2048), dim3(256), 0, stream>>>(
      x, wq, bq, wk, bk, wv, bv, rph, rpw, pw,
      x_bf, w_bf, pw_bf, rph_bf, rpw_bf, bias_all);
  qkv_gemm<<<dim3(32, 18), dim3(256), 0, stream>>>(
      x_bf, w_bf, bias_all, q_bf, k_bf, v_t);
  rel_kernel<<<dim3(NHD * 64, 2), dim3(256), 0, stream>>>(
      q_bf, rph_bf, rpw_bf, rel_hT, rel_w);
  flash_kernel<<<dim3(NHD * 64), dim3(256), 0, stream>>>(
      q_bf, k_bf, v_t, rel_hT, rel_w, ao_bf);
  proj_gemm<<<dim3(32, 6), dim3(256), 0, stream>>>(ao_bf, pw_bf, pb, out);
}